// Round 2
// baseline (7577.540 us; speedup 1.0000x reference)
//
#include <hip/hip_runtime.h>

// BiLSTMTagger on MI355X (gfx950) — 256 MB workspace budget.
// Chunked pipeline (16 chunks x 32 steps per layer) with FUSED overlap:
//   fused launch = 512 blocks x 128 thr:
//     blocks 0..255   : persistent lstm_scan for chunk c (unchanged protocol)
//     blocks 256..511 : GEMM role — gx for chunk c+1 (double-buffered gxc),
//                       plus (layer 2) classifier for chunk c-1.
//   Co-residency safety: <=512 regs/wave -> >=4 waves/CU -> 2 blocks/CU ->
//   all 512 blocks resident under ANY dispatch order. GEMM blocks never wait,
//   scan blocks wait only on each other -> no new deadlock edge.
//   gx layer1 gathers emb[x] directly (fp32->fp16 at staging) — no e buffer.
// Scan sync: XCD-LOCALITY AS AN OPTIMIZATION, NEVER AN ASSUMPTION.
//   Producers DUAL-STORE h granules and tags: sc0 (own XCD L2) + sc1 (LLC).
//   Tag polls alternate sc0/sc1. Correct under any block->XCD mapping.
// fp16 storage/MFMA, fp32 cell math.

typedef unsigned short u16;
typedef unsigned long long u64;
typedef _Float16 f16;
typedef __attribute__((ext_vector_type(8))) _Float16 f16x8;
typedef __attribute__((ext_vector_type(4))) float f32x4;

#define TT 512
#define HH 512
#define CH 32          // steps per chunk
#define NCH 16         // chunks
#define TSTR 16        // tag stride in ints: 64B line per tag

__device__ __forceinline__ u16 f2h(float f) { f16 h = (f16)f; return __builtin_bit_cast(u16, h); }
__device__ __forceinline__ float h2f(u16 s) { return (float)__builtin_bit_cast(f16, s); }
__device__ __forceinline__ float sigf(float x) { return 1.f / (1.f + __expf(-x)); }
__device__ __forceinline__ float tanhf_(float x) { return 1.f - 2.f / (__expf(2.f * x) + 1.f); }
__device__ __forceinline__ f32x4 zf4() { f32x4 z; z[0]=0.f; z[1]=0.f; z[2]=0.f; z[3]=0.f; return z; }

// sc0: bypass L1, coherent within this XCD's L2. sc1: bypass L2, LLC-coherent.
__device__ __forceinline__ void st16_sc0(u16* p, f16x8 v) {
  asm volatile("global_store_dwordx4 %0, %1, off sc0" :: "v"(p), "v"(v) : "memory");
}
__device__ __forceinline__ void st16_sc1(u16* p, f16x8 v) {
  asm volatile("global_store_dwordx4 %0, %1, off sc1" :: "v"(p), "v"(v) : "memory");
}
__device__ __forceinline__ f16x8 ld16_sc0(const u16* p) {
  f16x8 v;
  asm volatile("global_load_dwordx4 %0, %1, off sc0" : "=v"(v) : "v"(p) : "memory");
  return v;
}
__device__ __forceinline__ void sttag_sc0(int* p, int v) {
  asm volatile("global_store_dword %0, %1, off sc0" :: "v"(p), "v"(v) : "memory");
}
__device__ __forceinline__ void sttag_sc1(int* p, int v) {
  asm volatile("global_store_dword %0, %1, off sc1" :: "v"(p), "v"(v) : "memory");
}
__device__ __forceinline__ int ldtag_sc0(const int* p) {
  int v;
  asm volatile("global_load_dword %0, %1, off sc0" : "=v"(v) : "v"(p) : "memory");
  return v;
}
__device__ __forceinline__ int ldtag_sc1(const int* p) {
  int v;
  asm volatile("global_load_dword %0, %1, off sc1" : "=v"(v) : "v"(p) : "memory");
  return v;
}

// ---------------- utility kernels ----------------

struct CvtJob { const float* s; u16* d; int n; };
struct CvtJobs { CvtJob j[9]; };

__global__ void cvt_many(CvtJobs jobs) {
  CvtJob jb = jobs.j[blockIdx.y];
  int i = blockIdx.x * 256 + threadIdx.x;
  if (i < jb.n) jb.d[i] = f2h(jb.s[i]);
}

__global__ void bias_init(float* __restrict__ o, const float* __restrict__ b, int n) {
  int i = blockIdx.x * 256 + threadIdx.x;
  if (i < n) o[i] = b[i & 63];
}

__global__ void fill_diag(float* __restrict__ o, int n, float sentinel) {
  int i = blockIdx.x * 256 + threadIdx.x;
  if (i < n) o[i] = (i == 0) ? sentinel : 0.f;
}

// ---------------- GEMM role body (2 waves, 128 threads) ----------------
// gx tiles: 64x128, tiles = 2dirs x 64(tm) x 16(tn) = 2048. Row m = b*32+i.
//   lmode 0: A gathered from emb fp32 via x (layer1, K=256).
//   lmode 1: A gathered from out1 fp16 (layer2, K=1024).
// cls tiles (cls_s0>=0): 128x64, tiles = 2dirs x 32 = 64, K=512 per dir,
//   atomicAdd into bias-initialized dout with packed-seq masking.
// Register-pipelined staging (loads for kt+32 issued during MFMA of kt).

#define GX_LOAD(kt_) do { \
    if (lmode == 0) { \
      rf0 = *(const f32x4*)(Arf + (kt_) + kc); \
      rf1 = *(const f32x4*)(Arf + (kt_) + kc + 4); \
      rf2 = *(const f32x4*)(Arf + (kt_) + kc + 8); \
      rf3 = *(const f32x4*)(Arf + (kt_) + kc + 12); \
    } else { \
      ra0 = *(const uint4*)(Arh + (kt_) + kc); \
      ra1 = *(const uint4*)(Arh + (kt_) + kc + 8); \
    } \
    rb0 = *(const uint4*)(Br0 + (kt_) + kc); \
    rb1 = *(const uint4*)(Br0 + (kt_) + kc + 8); \
    rb2 = *(const uint4*)(Br1 + (kt_) + kc); \
    rb3 = *(const uint4*)(Br1 + (kt_) + kc + 8); \
  } while (0)

#define CLS_LOAD(kt_) do { \
    ca0 = *(const uint4*)(Arow + (kt_)); \
    ca1 = *(const uint4*)(Arow + (kt_) + 8); \
    ca2 = *(const uint4*)(Arow + (kt_) + 16); \
    ca3 = *(const uint4*)(Arow + (kt_) + 24); \
    cb0 = *(const uint4*)(Brw + (kt_) + kc); \
    cb1 = *(const uint4*)(Brw + (kt_) + kc + 8); \
  } while (0)

__device__ __forceinline__ void gemm_body(
    int gb, int nb, int tid,
    int lmode, int do_gx,
    const int* __restrict__ x, const float* __restrict__ emb,
    const u16* __restrict__ out1g,
    const u16* __restrict__ Bf, const u16* __restrict__ Bb,
    const float* __restrict__ biasf, const float* __restrict__ biasb,
    u16* __restrict__ gxn, int s0n, int K,
    int cls_s0, const u16* __restrict__ out2p, const u16* __restrict__ wclsp,
    float* __restrict__ dout, const int* __restrict__ len,
    u16* As, u16* Bs)
{
  const int lane = tid & 63;
  const int m16 = lane & 15, quad = lane >> 4;
  const int wv = tid >> 6;            // wave 0..1
  const int row = tid >> 1;           // 0..63
  const int kc = (tid & 1) * 16;
  const int ngx = do_gx ? 2048 : 0;
  const int ntl = ngx + (cls_s0 >= 0 ? 64 : 0);

  for (int t = gb; t < ntl; t += nb) {
    f32x4 acc[4][4];
#pragma unroll
    for (int a2 = 0; a2 < 4; ++a2)
#pragma unroll
      for (int c2 = 0; c2 < 4; ++c2) acc[a2][c2] = zf4();

    if (t < ngx) {
      // -------- gx tile --------
      const int dir = t >> 10, rem = t & 1023, tm = rem & 63, tn = rem >> 6;
      const u16* Bm = dir ? Bb : Bf;
      const float* bias = dir ? biasb : biasf;
      u16* Cp = gxn + (size_t)dir * 4096 * 2048;
      const int rowm = tm * 64 + row, b = rowm >> 5, ii = rowm & 31, s = s0n + ii;
      int pos;
      if (dir) { int p = len[b] - 1 - s; pos = p < 0 ? 0 : p; } else pos = s;
      const float* Arf = nullptr; const u16* Arh = nullptr;
      if (lmode == 0) Arf = emb + (size_t)x[b * TT + pos] * 256;
      else            Arh = out1g + ((size_t)b * TT + pos) * 1024;
      const u16* Br0 = Bm + (size_t)(tn * 128 + row) * K;
      const u16* Br1 = Bm + (size_t)(tn * 128 + row + 64) * K;

      f32x4 rf0, rf1, rf2, rf3; uint4 ra0, ra1, rb0, rb1, rb2, rb3;
      GX_LOAD(0);
      for (int kt = 0; kt < K; kt += 32) {
        if (lmode == 0) {
          f16x8 v0, v1;
#pragma unroll
          for (int j = 0; j < 4; ++j) {
            v0[j] = (f16)rf0[j]; v0[j + 4] = (f16)rf1[j];
            v1[j] = (f16)rf2[j]; v1[j + 4] = (f16)rf3[j];
          }
          *(f16x8*)&As[row * 40 + kc] = v0;
          *(f16x8*)&As[row * 40 + kc + 8] = v1;
        } else {
          *(uint4*)&As[row * 40 + kc]     = ra0;
          *(uint4*)&As[row * 40 + kc + 8] = ra1;
        }
        *(uint4*)&Bs[row * 40 + kc]            = rb0;
        *(uint4*)&Bs[row * 40 + kc + 8]        = rb1;
        *(uint4*)&Bs[(row + 64) * 40 + kc]     = rb2;
        *(uint4*)&Bs[(row + 64) * 40 + kc + 8] = rb3;
        __syncthreads();
        if (kt + 32 < K) GX_LOAD(kt + 32);
        f16x8 af[4], bfr[4];
#pragma unroll
        for (int mt = 0; mt < 4; ++mt)
          af[mt] = *(const f16x8*)&As[(mt * 16 + m16) * 40 + quad * 8];
#pragma unroll
        for (int nt = 0; nt < 4; ++nt)
          bfr[nt] = *(const f16x8*)&Bs[(wv * 64 + nt * 16 + m16) * 40 + quad * 8];
#pragma unroll
        for (int mt = 0; mt < 4; ++mt)
#pragma unroll
          for (int nt = 0; nt < 4; ++nt)
            acc[mt][nt] = __builtin_amdgcn_mfma_f32_16x16x32_f16(af[mt], bfr[nt], acc[mt][nt], 0, 0, 0);
        __syncthreads();
      }
#pragma unroll
      for (int mt = 0; mt < 4; ++mt)
#pragma unroll
        for (int nt = 0; nt < 4; ++nt) {
          const int n = tn * 128 + wv * 64 + nt * 16 + m16;
          const float bv = bias[n];
#pragma unroll
          for (int r = 0; r < 4; ++r) {
            const int mm = tm * 64 + mt * 16 + quad * 4 + r;
            Cp[(size_t)mm * 2048 + n] = f2h(acc[mt][nt][r] + bv);
          }
        }
    } else {
      // -------- cls tile --------
      const int tc = t - ngx;
      const int dir = tc >> 5, m0 = (tc & 31) * 128;
      const u16* Arow = out2p + (size_t)(m0 + tid) * 1024 + dir * 512;
      const u16* Brw  = wclsp + (size_t)row * 1024 + dir * 512;
      uint4 ca0, ca1, ca2, ca3, cb0, cb1;
      CLS_LOAD(0);
      for (int kt = 0; kt < 512; kt += 32) {
        *(uint4*)&Bs[tid * 40]      = ca0;
        *(uint4*)&Bs[tid * 40 + 8]  = ca1;
        *(uint4*)&Bs[tid * 40 + 16] = ca2;
        *(uint4*)&Bs[tid * 40 + 24] = ca3;
        *(uint4*)&As[row * 40 + kc]     = cb0;
        *(uint4*)&As[row * 40 + kc + 8] = cb1;
        __syncthreads();
        if (kt + 32 < 512) CLS_LOAD(kt + 32);
        f16x8 af[4], bfr[4];
#pragma unroll
        for (int mt = 0; mt < 4; ++mt)
          af[mt] = *(const f16x8*)&Bs[(wv * 64 + mt * 16 + m16) * 40 + quad * 8];
#pragma unroll
        for (int nt = 0; nt < 4; ++nt)
          bfr[nt] = *(const f16x8*)&As[(nt * 16 + m16) * 40 + quad * 8];
#pragma unroll
        for (int mt = 0; mt < 4; ++mt)
#pragma unroll
          for (int nt = 0; nt < 4; ++nt)
            acc[mt][nt] = __builtin_amdgcn_mfma_f32_16x16x32_f16(af[mt], bfr[nt], acc[mt][nt], 0, 0, 0);
        __syncthreads();
      }
#pragma unroll
      for (int mt = 0; mt < 4; ++mt)
#pragma unroll
        for (int nt = 0; nt < 4; ++nt) {
          const int n = nt * 16 + m16;
#pragma unroll
          for (int r = 0; r < 4; ++r) {
            const int m = m0 + wv * 64 + mt * 16 + quad * 4 + r;
            const int b = m >> 5, ii = m & 31, s = cls_s0 + ii;
            const int L = len[b];
            if (s < L) {
              const int pos = dir ? (L - 1 - s) : s;
              atomicAdd(&dout[((size_t)b * TT + pos) * 64 + n], acc[mt][nt][r]);
            }
          }
        }
    }
  }
}

__global__ __launch_bounds__(128, 2) void gemm_all(
    int lmode, int do_gx, const int* __restrict__ x, const float* __restrict__ emb,
    const u16* __restrict__ out1g,
    const u16* __restrict__ Bf, const u16* __restrict__ Bb,
    const float* __restrict__ biasf, const float* __restrict__ biasb,
    u16* __restrict__ gxn, int s0n, int K,
    int cls_s0, const u16* __restrict__ out2p, const u16* __restrict__ wclsp,
    float* __restrict__ dout, const int* __restrict__ len)
{
  __shared__ u16 As[64 * 40];
  __shared__ u16 Bs[128 * 40];
  gemm_body(blockIdx.x, gridDim.x, threadIdx.x, lmode, do_gx, x, emb, out1g,
            Bf, Bb, biasf, biasb, gxn, s0n, K, cls_s0, out2p, wclsp, dout, len,
            As, Bs);
}

// ---------------- fused: persistent BiLSTM scan chunk + overlapped GEMM ----
// blocks 0..255: scan (identical protocol to previous version).
// blocks 256..511: gemm_body for next chunk's gx (+ prev chunk's cls).

__global__ __launch_bounds__(128, 1) void fused(
    const u16* __restrict__ gxc, const u16* __restrict__ whh_f,
    const u16* __restrict__ whh_b, const int* __restrict__ len,
    u16* __restrict__ out_pos, u16* __restrict__ out_chunk,
    u16* __restrict__ hseq, u16* __restrict__ hcarry,
    float* __restrict__ cbuf, int* __restrict__ tags,
    int s0, int tagbase,
    int lmode, int do_gx, const int* __restrict__ x,
    const float* __restrict__ emb, const u16* __restrict__ out1g,
    const u16* __restrict__ Bf, const u16* __restrict__ Bb,
    const float* __restrict__ biasf, const float* __restrict__ biasb,
    u16* __restrict__ gxn, int s0n, int K,
    int cls_s0, const u16* __restrict__ out2p, const u16* __restrict__ wclsp,
    float* __restrict__ dout)
{
  __shared__ u16 As[64 * 40];
  __shared__ u16 Bs[128 * 40];
  __shared__ u16 tb[2][256];                 // 16x16 transpose tile per wave

  if (blockIdx.x >= 256) {
    gemm_body(blockIdx.x - 256, 256, threadIdx.x, lmode, do_gx, x, emb, out1g,
              Bf, Bb, biasf, biasb, gxn, s0n, K, cls_s0, out2p, wclsp, dout,
              len, As, Bs);
    return;
  }

  const int tid = threadIdx.x;
  const int bi = blockIdx.x;
  const int bg = bi & 7;                     // batch-group == XCD residue guess
  const int rank = bi >> 3;                  // 0..31 within residue
  const int dir = rank >> 4;
  const int role = rank & 15;
  const int b_base = bg * 16;
  const int grp = dir * 8 + bg;
  const int u_tile = role * 2 + (tid >> 6);  // 0..31 within group
  const int u_base = u_tile * 16;
  const int lane = tid & 63;
  const int m16 = lane & 15, quad = lane >> 4;
  const u16* gxd = gxc + (size_t)dir * 4096 * 2048;
  const u16* whh = dir ? whh_b : whh_f;
  u16* T = tb[tid >> 6];
  int* gtags = tags + grp * 32 * TSTR;
  int* mytag = gtags + u_tile * TSTR;

  // W_hh fragments: B[n=lane&15][k=quad*8+j] — 256 regs, AGPR-resident.
  f16x8 bf[4][16];
#pragma unroll
  for (int g = 0; g < 4; ++g) {
    const u16* wrow = whh + (size_t)(g * HH + u_base + m16) * HH + quad * 8;
#pragma unroll
    for (int ks = 0; ks < 16; ++ks)
      bf[g][ks] = *(const f16x8*)(wrow + ks * 32);
  }

  int lenr[4];
#pragma unroll
  for (int r = 0; r < 4; ++r) lenr[r] = len[b_base + quad * 4 + r];

  float cst[4];
  if (s0 == 0) {
#pragma unroll
    for (int r = 0; r < 4; ++r) cst[r] = 0.f;
  } else {
#pragma unroll
    for (int r = 0; r < 4; ++r)
      cst[r] = cbuf[(size_t)dir * 65536 + (b_base + quad * 4 + r) * HH + u_base + m16];
  }

  const u16* carry_rd = hcarry + (size_t)dir * 65536 + (b_base + m16) * HH + quad * 8;

  for (int i = 0; i < CH; ++i) {
    const int s = s0 + i;

    // gx prefetch (plain loads; drained by the first poll iteration)
    u16 gpre[4][4];
#pragma unroll
    for (int r = 0; r < 4; ++r) {
      const int batch = b_base + quad * 4 + r;
      const u16* gq = gxd + (size_t)(batch * CH + i) * 2048 + u_base + m16;
      gpre[r][0] = gq[0]; gpre[r][1] = gq[512];
      gpre[r][2] = gq[1024]; gpre[r][3] = gq[1536];
    }

    // A fragments = h[s-1]
    f16x8 a[16];
    if (i == 0) {
      if (s0 == 0) {
#pragma unroll
        for (int ks = 0; ks < 16; ++ks)
#pragma unroll
          for (int j = 0; j < 8; ++j) a[ks][j] = (f16)0.f;
      } else {
#pragma unroll
        for (int ks = 0; ks < 16; ++ks)
          a[ks] = *(const f16x8*)(carry_rd + ks * 32);   // kernel-boundary coherent
      }
    } else {
      // tag poll: alternate sc0 (fast when co-located) and sc1 (always-fresh LLC).
      const int want = tagbase + i;
      const int* myp = gtags + (lane & 31) * TSTR;
      int it = 0;
      while (true) {
        int t = (it & 1) ? ldtag_sc1(myp) : ldtag_sc0(myp);
        asm volatile("s_waitcnt vmcnt(0)" ::: "memory");
        if (__ballot(t < want) == 0ull) break;
        ++it;
        __builtin_amdgcn_s_sleep(1);
      }
      // h loads sc0: first-touch slots — dirty-L2 hit (co-located) or LLC fill.
      const u16* sb = hseq + ((size_t)(dir * CH + (i - 1)) * 128 + b_base + m16) * HH + quad * 8;
#pragma unroll
      for (int ks = 0; ks < 16; ++ks) a[ks] = ld16_sc0(sb + ks * 32);
      asm volatile("s_waitcnt vmcnt(0)" ::: "memory");
    }

    f32x4 a0 = zf4(), a1 = zf4(), a2 = zf4(), a3 = zf4();
#pragma unroll
    for (int ks = 0; ks < 16; ++ks) {
      a0 = __builtin_amdgcn_mfma_f32_16x16x32_f16(a[ks], bf[0][ks], a0, 0, 0, 0);
      a1 = __builtin_amdgcn_mfma_f32_16x16x32_f16(a[ks], bf[1][ks], a1, 0, 0, 0);
      a2 = __builtin_amdgcn_mfma_f32_16x16x32_f16(a[ks], bf[2][ks], a2, 0, 0, 0);
      a3 = __builtin_amdgcn_mfma_f32_16x16x32_f16(a[ks], bf[3][ks], a3, 0, 0, 0);
    }

    // cell math
    u16 hv[4];
#pragma unroll
    for (int r = 0; r < 4; ++r) {
      float gi = a0[r] + h2f(gpre[r][0]);
      float gf = a1[r] + h2f(gpre[r][1]);
      float gg = a2[r] + h2f(gpre[r][2]);
      float go = a3[r] + h2f(gpre[r][3]);
      float c = sigf(gf) * cst[r] + sigf(gi) * tanhf_(gg);
      cst[r] = c;
      hv[r] = f2h(sigf(go) * tanhf_(c));
    }

    // publish h: LDS 16x16 transpose -> dual-scope granule stores -> tags
#pragma unroll
    for (int r = 0; r < 4; ++r)
      T[(quad * 4 + r) * 16 + m16] = hv[r];
    if (lane < 32) {
      const int brow = lane >> 1, col8 = (lane & 1) * 8;
      f16x8 hrow = *(const f16x8*)&T[brow * 16 + col8];
      if (i == CH - 1) {
        *(f16x8*)(hcarry + (size_t)dir * 65536 + (b_base + brow) * HH + u_base + col8) = hrow;
      } else {
        u16* dst = hseq + ((size_t)(dir * CH + i) * 128 + b_base + brow) * HH + u_base + col8;
        st16_sc0(dst, hrow);
        st16_sc1(dst, hrow);
      }
    }
    if (i != CH - 1) {
      asm volatile("s_waitcnt vmcnt(0)" ::: "memory");   // h at L2 AND LLC
      if (lane == 0) { sttag_sc0(mytag, tagbase + i + 1); sttag_sc1(mytag, tagbase + i + 1); }
    }

    // outputs (plain stores, off the publish path)
#pragma unroll
    for (int r = 0; r < 4; ++r) {
      const int batch = b_base + quad * 4 + r;
      const int L = lenr[r];
      const bool valid = s < L;
      if (out_pos) {
        const int p = dir ? (L - 1 - s) : s;
        const int wrow = valid ? (p < 0 ? 0 : p) : s;
        out_pos[(size_t)(batch * TT + wrow) * 1024 + dir * 512 + u_base + m16]
            = valid ? hv[r] : (u16)0;
      } else {
        out_chunk[(size_t)(batch * CH + i) * 1024 + dir * 512 + u_base + m16] = hv[r];
      }
    }
  }

#pragma unroll
  for (int r = 0; r < 4; ++r)
    cbuf[(size_t)dir * 65536 + (b_base + quad * 4 + r) * HH + u_base + m16] = cst[r];
}

// ---------------- launch ----------------

extern "C" void kernel_launch(void* const* d_in, const int* in_sizes, int n_in,
                              void* d_out, int out_size, void* d_ws, size_t ws_size,
                              hipStream_t stream) {
  const int*   x      = (const int*)d_in[0];
  const int*   len    = (const int*)d_in[1];
  const float* emb    = (const float*)d_in[2];
  const float* Wih_f1 = (const float*)d_in[3];
  const float* Whh_f1 = (const float*)d_in[4];
  const float* b_f1   = (const float*)d_in[5];
  const float* Wih_b1 = (const float*)d_in[6];
  const float* Whh_b1 = (const float*)d_in[7];
  const float* b_b1   = (const float*)d_in[8];
  const float* Wih_f2 = (const float*)d_in[9];
  const float* Whh_f2 = (const float*)d_in[10];
  const float* b_f2   = (const float*)d_in[11];
  const float* Wih_b2 = (const float*)d_in[12];
  const float* Whh_b2 = (const float*)d_in[13];
  const float* b_b2   = (const float*)d_in[14];
  const float* W_cls  = (const float*)d_in[15];
  const float* b_cls  = (const float*)d_in[16];

  const size_t GXC1  = (size_t)2 * 4096 * 2048 * 2;     // 33.5 MB per parity
  const size_t OUT1  = (size_t)65536 * 1024 * 2;        // 128 MB
  const size_t OUT2  = (size_t)4096 * 1024 * 2;         // 8 MB per parity
  const size_t WTS   = (size_t)9502720 * 2;             // 18.1 MB
  const size_t HSEQ  = (size_t)2 * CH * 128 * 512 * 2;  // 8 MB
  const size_t HCAR  = (size_t)2 * 128 * 512 * 2;       // 256 KB
  const size_t TAGSZ = 16 * 32 * TSTR * 4;              // 32 KB
  const size_t NEED = 2 * GXC1 + OUT1 + 2 * OUT2 + WTS + HSEQ + HCAR + 524288 + TAGSZ;
  if (ws_size < NEED) {
    fill_diag<<<dim3((out_size + 255) / 256), dim3(256), 0, stream>>>(
        (float*)d_out, out_size, (float)(ws_size >> 20));
    return;
  }

  char* w = (char*)d_ws;
  u16* gxb0  = (u16*)w; w += GXC1;
  u16* gxb1  = (u16*)w; w += GXC1;
  u16* out1  = (u16*)w; w += OUT1;
  u16* o2b0  = (u16*)w; w += OUT2;
  u16* o2b1  = (u16*)w; w += OUT2;
  u16* wihf1 = (u16*)w; w += (size_t)2048 * 256 * 2;
  u16* wihb1 = (u16*)w; w += (size_t)2048 * 256 * 2;
  u16* whhf1 = (u16*)w; w += (size_t)2048 * 512 * 2;
  u16* whhb1 = (u16*)w; w += (size_t)2048 * 512 * 2;
  u16* wihf2 = (u16*)w; w += (size_t)2048 * 1024 * 2;
  u16* wihb2 = (u16*)w; w += (size_t)2048 * 1024 * 2;
  u16* whhf2 = (u16*)w; w += (size_t)2048 * 512 * 2;
  u16* whhb2 = (u16*)w; w += (size_t)2048 * 512 * 2;
  u16* wcls  = (u16*)w; w += (size_t)64 * 1024 * 2;
  u16* hseq  = (u16*)w; w += HSEQ;
  u16* hcarry = (u16*)w; w += HCAR;
  float* cbuf = (float*)w; w += 524288;
  int* tags  = (int*)w; w += TAGSZ;

  CvtJobs jobs = {{
    { Wih_f1, wihf1, 2048 * 256 }, { Wih_b1, wihb1, 2048 * 256 },
    { Whh_f1, whhf1, 2048 * 512 }, { Whh_b1, whhb1, 2048 * 512 },
    { Wih_f2, wihf2, 2048 * 1024 }, { Wih_b2, wihb2, 2048 * 1024 },
    { Whh_f2, whhf2, 2048 * 512 }, { Whh_b2, whhb2, 2048 * 512 },
    { W_cls,  wcls,  64 * 1024 },
  }};
  cvt_many<<<dim3(8192, 9), dim3(256), 0, stream>>>(jobs);
  bias_init<<<dim3(16384), dim3(256), 0, stream>>>((float*)d_out, b_cls, 65536 * 64);
  hipMemsetAsync(tags, 0, TAGSZ, stream);   // tags monotone within one launch set

  u16* gxb[2] = { gxb0, gxb1 };
  u16* o2b[2] = { o2b0, o2b1 };
  float* doutf = (float*)d_out;

  int seq = 0;
  // ---- layer 1 ----
  gemm_all<<<dim3(512), dim3(128), 0, stream>>>(
      0, 1, x, emb, nullptr, wihf1, wihb1, b_f1, b_b1,
      gxb[0], 0, 256, -1, nullptr, wcls, doutf, len);
  for (int c = 0; c < NCH; ++c) {
    fused<<<dim3(512), dim3(128), 0, stream>>>(
        gxb[c & 1], whhf1, whhb1, len, out1, nullptr, hseq, hcarry, cbuf, tags,
        c * CH, seq * CH,
        0, (c < NCH - 1) ? 1 : 0, x, emb, nullptr, wihf1, wihb1, b_f1, b_b1,
        gxb[(c + 1) & 1], (c + 1) * CH, 256,
        -1, nullptr, wcls, doutf);
    ++seq;
  }
  // ---- layer 2 + overlapped classifier ----
  gemm_all<<<dim3(512), dim3(128), 0, stream>>>(
      1, 1, x, emb, out1, wihf2, wihb2, b_f2, b_b2,
      gxb[0], 0, 1024, -1, nullptr, wcls, doutf, len);
  for (int c = 0; c < NCH; ++c) {
    fused<<<dim3(512), dim3(128), 0, stream>>>(
        gxb[c & 1], whhf2, whhb2, len, nullptr, o2b[c & 1], hseq, hcarry, cbuf, tags,
        c * CH, seq * CH,
        1, (c < NCH - 1) ? 1 : 0, x, emb, out1, wihf2, wihb2, b_f2, b_b2,
        gxb[(c + 1) & 1], (c + 1) * CH, 1024,
        (c >= 1) ? (c - 1) * CH : -1, o2b[(c & 1) ^ 1], wcls, doutf);
    ++seq;
  }
  // tail classifier for the last chunk
  gemm_all<<<dim3(512), dim3(128), 0, stream>>>(
      1, 0, x, emb, out1, wihf2, wihb2, b_f2, b_b2,
      gxb[0], 0, 1024, (NCH - 1) * CH, o2b[(NCH - 1) & 1], wcls, doutf, len);
}

// Round 7
// 6562.324 us; speedup vs baseline: 1.1547x; 1.1547x over previous
//
#include <hip/hip_runtime.h>

// BiLSTMTagger on MI355X (gfx950) — 256 MB workspace budget.
// Chunked pipeline (16 chunks x 32 steps per layer) with FUSED overlap:
//   fused launch = 512 blocks x 128 thr:
//     scan role  (bi&8)==0 : persistent lstm_scan for chunk c
//     gemm role  (bi&8)!=0 : gx for chunk c+1 (+ layer-2 classifier c-1)
//   ROLE SPLIT BY BIT 3: under round-robin dispatch, blocks b and b+256
//   share a CU and agree in bit 3 -> co-tenant pairs are role-identical
//   (scan CUs never host GEMM queues; fixes R2's 254us interference).
//   Co-residency: <=512 regs/wave -> 2 blocks/CU -> all 512 resident under
//   ANY mapping. GEMM never waits; scan waits only on scan. No deadlock.
// Scan sync: XCD-LOCALITY AS AN OPTIMIZATION, NEVER AN ASSUMPTION.
//   Split-scope publish: st_h sc0 -> vmcnt(0) -> tag sc0   (L2 ack ~300cy)
//                        st_h sc1 -> vmcnt(0) -> tag sc1   (LLC, off-path)
//   Remote consumers can only see tag values via LLC (tag_sc1), which is
//   ordered after h's sc1 store -> correct under any block->XCD mapping.
//   gx prefetch for step i+1 issued after step i's publish (HBM latency
//   hides under producer wait instead of sitting in the poll's vmcnt(0)).
// fp16 storage/MFMA, fp32 cell math.

typedef unsigned short u16;
typedef unsigned long long u64;
typedef _Float16 f16;
typedef __attribute__((ext_vector_type(8))) _Float16 f16x8;
typedef __attribute__((ext_vector_type(4))) float f32x4;

#define TT 512
#define HH 512
#define CH 32          // steps per chunk
#define NCH 16         // chunks
#define TSTR 16        // tag stride in ints: 64B line per tag

__device__ __forceinline__ u16 f2h(float f) { f16 h = (f16)f; return __builtin_bit_cast(u16, h); }
__device__ __forceinline__ float h2f(u16 s) { return (float)__builtin_bit_cast(f16, s); }
__device__ __forceinline__ float sigf(float x) { return 1.f / (1.f + __expf(-x)); }
__device__ __forceinline__ float tanhf_(float x) { return 1.f - 2.f / (__expf(2.f * x) + 1.f); }
__device__ __forceinline__ f32x4 zf4() { f32x4 z; z[0]=0.f; z[1]=0.f; z[2]=0.f; z[3]=0.f; return z; }

// sc0: bypass L1, coherent within this XCD's L2. sc1: bypass L2, LLC-coherent.
__device__ __forceinline__ void st16_sc0(u16* p, f16x8 v) {
  asm volatile("global_store_dwordx4 %0, %1, off sc0" :: "v"(p), "v"(v) : "memory");
}
__device__ __forceinline__ void st16_sc1(u16* p, f16x8 v) {
  asm volatile("global_store_dwordx4 %0, %1, off sc1" :: "v"(p), "v"(v) : "memory");
}
__device__ __forceinline__ f16x8 ld16_sc0(const u16* p) {
  f16x8 v;
  asm volatile("global_load_dwordx4 %0, %1, off sc0" : "=v"(v) : "v"(p) : "memory");
  return v;
}
__device__ __forceinline__ void sttag_sc0(int* p, int v) {
  asm volatile("global_store_dword %0, %1, off sc0" :: "v"(p), "v"(v) : "memory");
}
__device__ __forceinline__ void sttag_sc1(int* p, int v) {
  asm volatile("global_store_dword %0, %1, off sc1" :: "v"(p), "v"(v) : "memory");
}
__device__ __forceinline__ int ldtag_sc0(const int* p) {
  int v;
  asm volatile("global_load_dword %0, %1, off sc0" : "=v"(v) : "v"(p) : "memory");
  return v;
}
__device__ __forceinline__ int ldtag_sc1(const int* p) {
  int v;
  asm volatile("global_load_dword %0, %1, off sc1" : "=v"(v) : "v"(p) : "memory");
  return v;
}

// ---------------- utility kernels ----------------

struct CvtJob { const float* s; u16* d; int n; };
struct CvtJobs { CvtJob j[9]; };

__global__ void cvt_many(CvtJobs jobs) {
  CvtJob jb = jobs.j[blockIdx.y];
  int i = blockIdx.x * 256 + threadIdx.x;
  if (i < jb.n) jb.d[i] = f2h(jb.s[i]);
}

__global__ void bias_init(float* __restrict__ o, const float* __restrict__ b, int n) {
  int i = blockIdx.x * 256 + threadIdx.x;
  if (i < n) o[i] = b[i & 63];
}

__global__ void fill_diag(float* __restrict__ o, int n, float sentinel) {
  int i = blockIdx.x * 256 + threadIdx.x;
  if (i < n) o[i] = (i == 0) ? sentinel : 0.f;
}

// ---------------- GEMM role body (2 waves, 128 threads) ----------------
// gx tiles: 64x128, tiles = 2dirs x 64(tm) x 16(tn) = 2048. Row m = b*32+i.
//   lmode 0: A gathered from emb fp32 via x (layer1, K=256).
//   lmode 1: A gathered from out1 fp16 (layer2, K=1024).
// cls tiles (cls_s0>=0): 128x64, tiles = 2dirs x 32 = 64, K=512 per dir,
//   atomicAdd into bias-initialized dout with packed-seq masking.
// Register-pipelined staging (loads for kt+32 issued during MFMA of kt).

#define GX_LOAD(kt_) do { \
    if (lmode == 0) { \
      rf0 = *(const f32x4*)(Arf + (kt_) + kc); \
      rf1 = *(const f32x4*)(Arf + (kt_) + kc + 4); \
      rf2 = *(const f32x4*)(Arf + (kt_) + kc + 8); \
      rf3 = *(const f32x4*)(Arf + (kt_) + kc + 12); \
    } else { \
      ra0 = *(const uint4*)(Arh + (kt_) + kc); \
      ra1 = *(const uint4*)(Arh + (kt_) + kc + 8); \
    } \
    rb0 = *(const uint4*)(Br0 + (kt_) + kc); \
    rb1 = *(const uint4*)(Br0 + (kt_) + kc + 8); \
    rb2 = *(const uint4*)(Br1 + (kt_) + kc); \
    rb3 = *(const uint4*)(Br1 + (kt_) + kc + 8); \
  } while (0)

#define CLS_LOAD(kt_) do { \
    ca0 = *(const uint4*)(Arow + (kt_)); \
    ca1 = *(const uint4*)(Arow + (kt_) + 8); \
    ca2 = *(const uint4*)(Arow + (kt_) + 16); \
    ca3 = *(const uint4*)(Arow + (kt_) + 24); \
    cb0 = *(const uint4*)(Brw + (kt_) + kc); \
    cb1 = *(const uint4*)(Brw + (kt_) + kc + 8); \
  } while (0)

__device__ __forceinline__ void gemm_body(
    int gb, int nb, int tid,
    int lmode, int do_gx,
    const int* __restrict__ x, const float* __restrict__ emb,
    const u16* __restrict__ out1g,
    const u16* __restrict__ Bf, const u16* __restrict__ Bb,
    const float* __restrict__ biasf, const float* __restrict__ biasb,
    u16* __restrict__ gxn, int s0n, int K,
    int cls_s0, const u16* __restrict__ out2p, const u16* __restrict__ wclsp,
    float* __restrict__ dout, const int* __restrict__ len,
    u16* As, u16* Bs)
{
  const int lane = tid & 63;
  const int m16 = lane & 15, quad = lane >> 4;
  const int wv = tid >> 6;            // wave 0..1
  const int row = tid >> 1;           // 0..63
  const int kc = (tid & 1) * 16;
  const int ngx = do_gx ? 2048 : 0;
  const int ntl = ngx + (cls_s0 >= 0 ? 64 : 0);

  for (int t = gb; t < ntl; t += nb) {
    f32x4 acc[4][4];
#pragma unroll
    for (int a2 = 0; a2 < 4; ++a2)
#pragma unroll
      for (int c2 = 0; c2 < 4; ++c2) acc[a2][c2] = zf4();

    if (t < ngx) {
      // -------- gx tile --------
      const int dir = t >> 10, rem = t & 1023, tm = rem & 63, tn = rem >> 6;
      const u16* Bm = dir ? Bb : Bf;
      const float* bias = dir ? biasb : biasf;
      u16* Cp = gxn + (size_t)dir * 4096 * 2048;
      const int rowm = tm * 64 + row, b = rowm >> 5, ii = rowm & 31, s = s0n + ii;
      int pos;
      if (dir) { int p = len[b] - 1 - s; pos = p < 0 ? 0 : p; } else pos = s;
      const float* Arf = nullptr; const u16* Arh = nullptr;
      if (lmode == 0) Arf = emb + (size_t)x[b * TT + pos] * 256;
      else            Arh = out1g + ((size_t)b * TT + pos) * 1024;
      const u16* Br0 = Bm + (size_t)(tn * 128 + row) * K;
      const u16* Br1 = Bm + (size_t)(tn * 128 + row + 64) * K;

      f32x4 rf0, rf1, rf2, rf3; uint4 ra0, ra1, rb0, rb1, rb2, rb3;
      GX_LOAD(0);
      for (int kt = 0; kt < K; kt += 32) {
        if (lmode == 0) {
          f16x8 v0, v1;
#pragma unroll
          for (int j = 0; j < 4; ++j) {
            v0[j] = (f16)rf0[j]; v0[j + 4] = (f16)rf1[j];
            v1[j] = (f16)rf2[j]; v1[j + 4] = (f16)rf3[j];
          }
          *(f16x8*)&As[row * 40 + kc] = v0;
          *(f16x8*)&As[row * 40 + kc + 8] = v1;
        } else {
          *(uint4*)&As[row * 40 + kc]     = ra0;
          *(uint4*)&As[row * 40 + kc + 8] = ra1;
        }
        *(uint4*)&Bs[row * 40 + kc]            = rb0;
        *(uint4*)&Bs[row * 40 + kc + 8]        = rb1;
        *(uint4*)&Bs[(row + 64) * 40 + kc]     = rb2;
        *(uint4*)&Bs[(row + 64) * 40 + kc + 8] = rb3;
        __syncthreads();
        if (kt + 32 < K) GX_LOAD(kt + 32);
        f16x8 af[4], bfr[4];
#pragma unroll
        for (int mt = 0; mt < 4; ++mt)
          af[mt] = *(const f16x8*)&As[(mt * 16 + m16) * 40 + quad * 8];
#pragma unroll
        for (int nt = 0; nt < 4; ++nt)
          bfr[nt] = *(const f16x8*)&Bs[(wv * 64 + nt * 16 + m16) * 40 + quad * 8];
#pragma unroll
        for (int mt = 0; mt < 4; ++mt)
#pragma unroll
          for (int nt = 0; nt < 4; ++nt)
            acc[mt][nt] = __builtin_amdgcn_mfma_f32_16x16x32_f16(af[mt], bfr[nt], acc[mt][nt], 0, 0, 0);
        __syncthreads();
      }
#pragma unroll
      for (int mt = 0; mt < 4; ++mt)
#pragma unroll
        for (int nt = 0; nt < 4; ++nt) {
          const int n = tn * 128 + wv * 64 + nt * 16 + m16;
          const float bv = bias[n];
#pragma unroll
          for (int r = 0; r < 4; ++r) {
            const int mm = tm * 64 + mt * 16 + quad * 4 + r;
            Cp[(size_t)mm * 2048 + n] = f2h(acc[mt][nt][r] + bv);
          }
        }
    } else {
      // -------- cls tile --------
      const int tc = t - ngx;
      const int dir = tc >> 5, m0 = (tc & 31) * 128;
      const u16* Arow = out2p + (size_t)(m0 + tid) * 1024 + dir * 512;
      const u16* Brw  = wclsp + (size_t)row * 1024 + dir * 512;
      uint4 ca0, ca1, ca2, ca3, cb0, cb1;
      CLS_LOAD(0);
      for (int kt = 0; kt < 512; kt += 32) {
        *(uint4*)&Bs[tid * 40]      = ca0;
        *(uint4*)&Bs[tid * 40 + 8]  = ca1;
        *(uint4*)&Bs[tid * 40 + 16] = ca2;
        *(uint4*)&Bs[tid * 40 + 24] = ca3;
        *(uint4*)&As[row * 40 + kc]     = cb0;
        *(uint4*)&As[row * 40 + kc + 8] = cb1;
        __syncthreads();
        if (kt + 32 < 512) CLS_LOAD(kt + 32);
        f16x8 af[4], bfr[4];
#pragma unroll
        for (int mt = 0; mt < 4; ++mt)
          af[mt] = *(const f16x8*)&Bs[(wv * 64 + mt * 16 + m16) * 40 + quad * 8];
#pragma unroll
        for (int nt = 0; nt < 4; ++nt)
          bfr[nt] = *(const f16x8*)&As[(nt * 16 + m16) * 40 + quad * 8];
#pragma unroll
        for (int mt = 0; mt < 4; ++mt)
#pragma unroll
          for (int nt = 0; nt < 4; ++nt)
            acc[mt][nt] = __builtin_amdgcn_mfma_f32_16x16x32_f16(af[mt], bfr[nt], acc[mt][nt], 0, 0, 0);
        __syncthreads();
      }
#pragma unroll
      for (int mt = 0; mt < 4; ++mt)
#pragma unroll
        for (int nt = 0; nt < 4; ++nt) {
          const int n = nt * 16 + m16;
#pragma unroll
          for (int r = 0; r < 4; ++r) {
            const int m = m0 + wv * 64 + mt * 16 + quad * 4 + r;
            const int b = m >> 5, ii = m & 31, s = cls_s0 + ii;
            const int L = len[b];
            if (s < L) {
              const int pos = dir ? (L - 1 - s) : s;
              atomicAdd(&dout[((size_t)b * TT + pos) * 64 + n], acc[mt][nt][r]);
            }
          }
        }
    }
  }
}

__global__ __launch_bounds__(128, 2) void gemm_all(
    int lmode, int do_gx, const int* __restrict__ x, const float* __restrict__ emb,
    const u16* __restrict__ out1g,
    const u16* __restrict__ Bf, const u16* __restrict__ Bb,
    const float* __restrict__ biasf, const float* __restrict__ biasb,
    u16* __restrict__ gxn, int s0n, int K,
    int cls_s0, const u16* __restrict__ out2p, const u16* __restrict__ wclsp,
    float* __restrict__ dout, const int* __restrict__ len)
{
  __shared__ u16 As[64 * 40];
  __shared__ u16 Bs[128 * 40];
  gemm_body(blockIdx.x, gridDim.x, threadIdx.x, lmode, do_gx, x, emb, out1g,
            Bf, Bb, biasf, biasb, gxn, s0n, K, cls_s0, out2p, wclsp, dout, len,
            As, Bs);
}

// ---------------- fused: persistent BiLSTM scan chunk + overlapped GEMM ----
// Role by BIT 3 of blockIdx: (bi&8)==0 -> scan, else gemm. Virtual index
// vix = (bi>>4)*8 + (bi&7) is 0..255 within each role and preserves the
// XCD residue (bi&7) for the scan's locality groups.

__global__ __launch_bounds__(128, 1) void fused(
    const u16* __restrict__ gxc, const u16* __restrict__ whh_f,
    const u16* __restrict__ whh_b, const int* __restrict__ len,
    u16* __restrict__ out_pos, u16* __restrict__ out_chunk,
    u16* __restrict__ hseq, u16* __restrict__ hcarry,
    float* __restrict__ cbuf, int* __restrict__ tags,
    int s0, int tagbase,
    int lmode, int do_gx, const int* __restrict__ x,
    const float* __restrict__ emb, const u16* __restrict__ out1g,
    const u16* __restrict__ Bf, const u16* __restrict__ Bb,
    const float* __restrict__ biasf, const float* __restrict__ biasb,
    u16* __restrict__ gxn, int s0n, int K,
    int cls_s0, const u16* __restrict__ out2p, const u16* __restrict__ wclsp,
    float* __restrict__ dout)
{
  __shared__ u16 As[64 * 40];
  __shared__ u16 Bs[128 * 40];
  __shared__ u16 tb[2][256];                 // 16x16 transpose tile per wave

  const int bix = blockIdx.x;
  const int vix = ((bix >> 4) << 3) | (bix & 7);   // 0..255 within role

  if (bix & 8) {
    gemm_body(vix, 256, threadIdx.x, lmode, do_gx, x, emb, out1g,
              Bf, Bb, biasf, biasb, gxn, s0n, K, cls_s0, out2p, wclsp, dout,
              len, As, Bs);
    return;
  }

  const int tid = threadIdx.x;
  const int bg = vix & 7;                    // batch-group == XCD residue guess
  const int rank = vix >> 3;                 // 0..31 within residue
  const int dir = rank >> 4;
  const int role = rank & 15;
  const int b_base = bg * 16;
  const int grp = dir * 8 + bg;
  const int u_tile = role * 2 + (tid >> 6);  // 0..31 within group
  const int u_base = u_tile * 16;
  const int lane = tid & 63;
  const int m16 = lane & 15, quad = lane >> 4;
  const u16* gxd = gxc + (size_t)dir * 4096 * 2048;
  const u16* whh = dir ? whh_b : whh_f;
  u16* T = tb[tid >> 6];
  int* gtags = tags + grp * 32 * TSTR;
  int* mytag = gtags + u_tile * TSTR;

  // W_hh fragments: B[n=lane&15][k=quad*8+j] — 256 regs, AGPR-resident.
  f16x8 bf[4][16];
#pragma unroll
  for (int g = 0; g < 4; ++g) {
    const u16* wrow = whh + (size_t)(g * HH + u_base + m16) * HH + quad * 8;
#pragma unroll
    for (int ks = 0; ks < 16; ++ks)
      bf[g][ks] = *(const f16x8*)(wrow + ks * 32);
  }

  int lenr[4];
#pragma unroll
  for (int r = 0; r < 4; ++r) lenr[r] = len[b_base + quad * 4 + r];

  float cst[4];
  if (s0 == 0) {
#pragma unroll
    for (int r = 0; r < 4; ++r) cst[r] = 0.f;
  } else {
#pragma unroll
    for (int r = 0; r < 4; ++r)
      cst[r] = cbuf[(size_t)dir * 65536 + (b_base + quad * 4 + r) * HH + u_base + m16];
  }

  const u16* carry_rd = hcarry + (size_t)dir * 65536 + (b_base + m16) * HH + quad * 8;

  // gx prefetch for step 0 (drained by first use in cell math)
  u16 gpre[4][4];
#pragma unroll
  for (int r = 0; r < 4; ++r) {
    const int batch = b_base + quad * 4 + r;
    const u16* gq = gxd + (size_t)(batch * CH + 0) * 2048 + u_base + m16;
    gpre[r][0] = gq[0]; gpre[r][1] = gq[512];
    gpre[r][2] = gq[1024]; gpre[r][3] = gq[1536];
  }

  for (int i = 0; i < CH; ++i) {
    const int s = s0 + i;

    // A fragments = h[s-1]
    f16x8 a[16];
    if (i == 0) {
      if (s0 == 0) {
#pragma unroll
        for (int ks = 0; ks < 16; ++ks)
#pragma unroll
          for (int j = 0; j < 8; ++j) a[ks][j] = (f16)0.f;
      } else {
#pragma unroll
        for (int ks = 0; ks < 16; ++ks)
          a[ks] = *(const f16x8*)(carry_rd + ks * 32);   // kernel-boundary coherent
      }
    } else {
      // tag poll: alternate sc0 (fast when co-located) and sc1 (always-fresh LLC).
      const int want = tagbase + i;
      const int* myp = gtags + (lane & 31) * TSTR;
      int it = 0;
      while (true) {
        int t = (it & 1) ? ldtag_sc1(myp) : ldtag_sc0(myp);
        asm volatile("s_waitcnt vmcnt(0)" ::: "memory");
        if (__ballot(t < want) == 0ull) break;
        ++it;
        __builtin_amdgcn_s_sleep(1);
      }
      // h loads sc0: first-touch slots this dispatch — dirty-L2 hit
      // (co-located producer) or LLC fill (sc1 order guarantees currency).
      const u16* sb = hseq + ((size_t)(dir * CH + (i - 1)) * 128 + b_base + m16) * HH + quad * 8;
#pragma unroll
      for (int ks = 0; ks < 16; ++ks) a[ks] = ld16_sc0(sb + ks * 32);
      asm volatile("s_waitcnt vmcnt(0)" ::: "memory");
    }

    f32x4 a0 = zf4(), a1 = zf4(), a2 = zf4(), a3 = zf4();
#pragma unroll
    for (int ks = 0; ks < 16; ++ks) {
      a0 = __builtin_amdgcn_mfma_f32_16x16x32_f16(a[ks], bf[0][ks], a0, 0, 0, 0);
      a1 = __builtin_amdgcn_mfma_f32_16x16x32_f16(a[ks], bf[1][ks], a1, 0, 0, 0);
      a2 = __builtin_amdgcn_mfma_f32_16x16x32_f16(a[ks], bf[2][ks], a2, 0, 0, 0);
      a3 = __builtin_amdgcn_mfma_f32_16x16x32_f16(a[ks], bf[3][ks], a3, 0, 0, 0);
    }

    // cell math
    u16 hv[4];
#pragma unroll
    for (int r = 0; r < 4; ++r) {
      float gi = a0[r] + h2f(gpre[r][0]);
      float gf = a1[r] + h2f(gpre[r][1]);
      float gg = a2[r] + h2f(gpre[r][2]);
      float go = a3[r] + h2f(gpre[r][3]);
      float c = sigf(gf) * cst[r] + sigf(gi) * tanhf_(gg);
      cst[r] = c;
      hv[r] = f2h(sigf(go) * tanhf_(c));
    }

    // publish h: LDS 16x16 transpose -> split-scope stores + tags
#pragma unroll
    for (int r = 0; r < 4; ++r)
      T[(quad * 4 + r) * 16 + m16] = hv[r];
    if (i == CH - 1) {
      if (lane < 32) {
        const int brow = lane >> 1, col8 = (lane & 1) * 8;
        f16x8 hrow = *(const f16x8*)&T[brow * 16 + col8];
        *(f16x8*)(hcarry + (size_t)dir * 65536 + (b_base + brow) * HH + u_base + col8) = hrow;
      }
    } else {
      u16* dst = nullptr; f16x8 hrow;
      if (lane < 32) {
        const int brow = lane >> 1, col8 = (lane & 1) * 8;
        hrow = *(const f16x8*)&T[brow * 16 + col8];
        dst = hseq + ((size_t)(dir * CH + i) * 128 + b_base + brow) * HH + u_base + col8;
        st16_sc0(dst, hrow);
      }
      asm volatile("s_waitcnt vmcnt(0)" ::: "memory");   // h at own-XCD L2
      if (lane == 0) sttag_sc0(mytag, tagbase + i + 1);
      if (lane < 32) st16_sc1(dst, hrow);
      asm volatile("s_waitcnt vmcnt(0)" ::: "memory");   // h at LLC
      if (lane == 0) sttag_sc1(mytag, tagbase + i + 1);
    }

    // gx prefetch for step i+1 (issued early; drained by next poll/use)
    if (i + 1 < CH) {
#pragma unroll
      for (int r = 0; r < 4; ++r) {
        const int batch = b_base + quad * 4 + r;
        const u16* gq = gxd + (size_t)(batch * CH + (i + 1)) * 2048 + u_base + m16;
        gpre[r][0] = gq[0]; gpre[r][1] = gq[512];
        gpre[r][2] = gq[1024]; gpre[r][3] = gq[1536];
      }
    }

    // outputs (plain stores, off the publish path)
#pragma unroll
    for (int r = 0; r < 4; ++r) {
      const int batch = b_base + quad * 4 + r;
      const int L = lenr[r];
      const bool valid = s < L;
      if (out_pos) {
        const int p = dir ? (L - 1 - s) : s;
        const int wrow = valid ? (p < 0 ? 0 : p) : s;
        out_pos[(size_t)(batch * TT + wrow) * 1024 + dir * 512 + u_base + m16]
            = valid ? hv[r] : (u16)0;
      } else {
        out_chunk[(size_t)(batch * CH + i) * 1024 + dir * 512 + u_base + m16] = hv[r];
      }
    }
  }

#pragma unroll
  for (int r = 0; r < 4; ++r)
    cbuf[(size_t)dir * 65536 + (b_base + quad * 4 + r) * HH + u_base + m16] = cst[r];
}

// ---------------- launch ----------------

extern "C" void kernel_launch(void* const* d_in, const int* in_sizes, int n_in,
                              void* d_out, int out_size, void* d_ws, size_t ws_size,
                              hipStream_t stream) {
  const int*   x      = (const int*)d_in[0];
  const int*   len    = (const int*)d_in[1];
  const float* emb    = (const float*)d_in[2];
  const float* Wih_f1 = (const float*)d_in[3];
  const float* Whh_f1 = (const float*)d_in[4];
  const float* b_f1   = (const float*)d_in[5];
  const float* Wih_b1 = (const float*)d_in[6];
  const float* Whh_b1 = (const float*)d_in[7];
  const float* b_b1   = (const float*)d_in[8];
  const float* Wih_f2 = (const float*)d_in[9];
  const float* Whh_f2 = (const float*)d_in[10];
  const float* b_f2   = (const float*)d_in[11];
  const float* Wih_b2 = (const float*)d_in[12];
  const float* Whh_b2 = (const float*)d_in[13];
  const float* b_b2   = (const float*)d_in[14];
  const float* W_cls  = (const float*)d_in[15];
  const float* b_cls  = (const float*)d_in[16];

  const size_t GXC1  = (size_t)2 * 4096 * 2048 * 2;     // 33.5 MB per parity
  const size_t OUT1  = (size_t)65536 * 1024 * 2;        // 128 MB
  const size_t OUT2  = (size_t)4096 * 1024 * 2;         // 8 MB per parity
  const size_t WTS   = (size_t)9502720 * 2;             // 18.1 MB
  const size_t HSEQ  = (size_t)2 * CH * 128 * 512 * 2;  // 8 MB
  const size_t HCAR  = (size_t)2 * 128 * 512 * 2;       // 256 KB
  const size_t TAGSZ = 16 * 32 * TSTR * 4;              // 32 KB
  const size_t NEED = 2 * GXC1 + OUT1 + 2 * OUT2 + WTS + HSEQ + HCAR + 524288 + TAGSZ;
  if (ws_size < NEED) {
    fill_diag<<<dim3((out_size + 255) / 256), dim3(256), 0, stream>>>(
        (float*)d_out, out_size, (float)(ws_size >> 20));
    return;
  }

  char* w = (char*)d_ws;
  u16* gxb0  = (u16*)w; w += GXC1;
  u16* gxb1  = (u16*)w; w += GXC1;
  u16* out1  = (u16*)w; w += OUT1;
  u16* o2b0  = (u16*)w; w += OUT2;
  u16* o2b1  = (u16*)w; w += OUT2;
  u16* wihf1 = (u16*)w; w += (size_t)2048 * 256 * 2;
  u16* wihb1 = (u16*)w; w += (size_t)2048 * 256 * 2;
  u16* whhf1 = (u16*)w; w += (size_t)2048 * 512 * 2;
  u16* whhb1 = (u16*)w; w += (size_t)2048 * 512 * 2;
  u16* wihf2 = (u16*)w; w += (size_t)2048 * 1024 * 2;
  u16* wihb2 = (u16*)w; w += (size_t)2048 * 1024 * 2;
  u16* whhf2 = (u16*)w; w += (size_t)2048 * 512 * 2;
  u16* whhb2 = (u16*)w; w += (size_t)2048 * 512 * 2;
  u16* wcls  = (u16*)w; w += (size_t)64 * 1024 * 2;
  u16* hseq  = (u16*)w; w += HSEQ;
  u16* hcarry = (u16*)w; w += HCAR;
  float* cbuf = (float*)w; w += 524288;
  int* tags  = (int*)w; w += TAGSZ;

  CvtJobs jobs = {{
    { Wih_f1, wihf1, 2048 * 256 }, { Wih_b1, wihb1, 2048 * 256 },
    { Whh_f1, whhf1, 2048 * 512 }, { Whh_b1, whhb1, 2048 * 512 },
    { Wih_f2, wihf2, 2048 * 1024 }, { Wih_b2, wihb2, 2048 * 1024 },
    { Whh_f2, whhf2, 2048 * 512 }, { Whh_b2, whhb2, 2048 * 512 },
    { W_cls,  wcls,  64 * 1024 },
  }};
  cvt_many<<<dim3(8192, 9), dim3(256), 0, stream>>>(jobs);
  bias_init<<<dim3(16384), dim3(256), 0, stream>>>((float*)d_out, b_cls, 65536 * 64);
  hipMemsetAsync(tags, 0, TAGSZ, stream);   // tags monotone within one launch set

  u16* gxb[2] = { gxb0, gxb1 };
  u16* o2b[2] = { o2b0, o2b1 };
  float* doutf = (float*)d_out;

  int seq = 0;
  // ---- layer 1 ----
  gemm_all<<<dim3(2048), dim3(128), 0, stream>>>(
      0, 1, x, emb, nullptr, wihf1, wihb1, b_f1, b_b1,
      gxb[0], 0, 256, -1, nullptr, wcls, doutf, len);
  for (int c = 0; c < NCH; ++c) {
    fused<<<dim3(512), dim3(128), 0, stream>>>(
        gxb[c & 1], whhf1, whhb1, len, out1, nullptr, hseq, hcarry, cbuf, tags,
        c * CH, seq * CH,
        0, (c < NCH - 1) ? 1 : 0, x, emb, nullptr, wihf1, wihb1, b_f1, b_b1,
        gxb[(c + 1) & 1], (c + 1) * CH, 256,
        -1, nullptr, wcls, doutf);
    ++seq;
  }
  // ---- layer 2 + overlapped classifier ----
  gemm_all<<<dim3(2048), dim3(128), 0, stream>>>(
      1, 1, x, emb, out1, wihf2, wihb2, b_f2, b_b2,
      gxb[0], 0, 1024, -1, nullptr, wcls, doutf, len);
  for (int c = 0; c < NCH; ++c) {
    fused<<<dim3(512), dim3(128), 0, stream>>>(
        gxb[c & 1], whhf2, whhb2, len, nullptr, o2b[c & 1], hseq, hcarry, cbuf, tags,
        c * CH, seq * CH,
        1, (c < NCH - 1) ? 1 : 0, x, emb, out1, wihf2, wihb2, b_f2, b_b2,
        gxb[(c + 1) & 1], (c + 1) * CH, 1024,
        (c >= 1) ? (c - 1) * CH : -1, o2b[(c & 1) ^ 1], wcls, doutf);
    ++seq;
  }
  // tail classifier for the last chunk
  gemm_all<<<dim3(64), dim3(128), 0, stream>>>(
      1, 0, x, emb, out1, wihf2, wihb2, b_f2, b_b2,
      gxb[0], 0, 1024, (NCH - 1) * CH, o2b[(NCH - 1) & 1], wcls, doutf, len);
}

// Round 8
// 6299.990 us; speedup vs baseline: 1.2028x; 1.0416x over previous
//
#include <hip/hip_runtime.h>

// BiLSTMTagger on MI355X (gfx950) — 256 MB workspace budget.
// Chunked pipeline (16 chunks x 32 steps per layer) with FUSED overlap:
//   fused launch = 512 blocks x 128 thr, ROLE SPLIT BY XCD RESIDUE:
//     scan role  (bi&7)<4  : persistent lstm_scan for chunk c (XCDs 0-3
//                            under the round-robin dispatch guess)
//     gemm role  (bi&7)>=4 : gx for chunk c+1 (+ layer-2 classifier c-1)
//                            (XCDs 4-7)
//   R7 measured bit-3 CU-split at 210us/dispatch (254 -> 210): CU-level
//   interference was minor. This round isolates XCD-level L2/fabric QoS:
//   GEMM streaming traffic now touches only L2s 4-7; scan L2s stay clean.
//   Co-tenant pairs {b, b+256} agree in bi&7 -> role-homogeneous CUs too.
//   Co-residency: <=512 regs/wave -> 2 blocks/CU -> all 512 resident under
//   ANY mapping. GEMM never waits; scan waits only on scan. No deadlock.
//   If the XCD guess is wrong: correctness unaffected (dual-store protocol),
//   perf degenerates to ~R2/R7 levels.
// Scan sync: XCD-LOCALITY AS AN OPTIMIZATION, NEVER AN ASSUMPTION.
//   Split-scope publish: st_h sc0 -> vmcnt(0) -> tag sc0   (L2 ack)
//                        st_h sc1 -> vmcnt(0) -> tag sc1   (LLC, off-path)
//   Remote consumers can only see tag values via LLC (tag_sc1), which is
//   ordered after h's sc1 store -> correct under any block->XCD mapping.
// fp16 storage/MFMA, fp32 cell math.

typedef unsigned short u16;
typedef unsigned long long u64;
typedef _Float16 f16;
typedef __attribute__((ext_vector_type(8))) _Float16 f16x8;
typedef __attribute__((ext_vector_type(4))) float f32x4;

#define TT 512
#define HH 512
#define CH 32          // steps per chunk
#define NCH 16         // chunks
#define TSTR 16        // tag stride in ints: 64B line per tag

__device__ __forceinline__ u16 f2h(float f) { f16 h = (f16)f; return __builtin_bit_cast(u16, h); }
__device__ __forceinline__ float h2f(u16 s) { return (float)__builtin_bit_cast(f16, s); }
__device__ __forceinline__ float sigf(float x) { return 1.f / (1.f + __expf(-x)); }
__device__ __forceinline__ float tanhf_(float x) { return 1.f - 2.f / (__expf(2.f * x) + 1.f); }
__device__ __forceinline__ f32x4 zf4() { f32x4 z; z[0]=0.f; z[1]=0.f; z[2]=0.f; z[3]=0.f; return z; }

// sc0: bypass L1, coherent within this XCD's L2. sc1: bypass L2, LLC-coherent.
__device__ __forceinline__ void st16_sc0(u16* p, f16x8 v) {
  asm volatile("global_store_dwordx4 %0, %1, off sc0" :: "v"(p), "v"(v) : "memory");
}
__device__ __forceinline__ void st16_sc1(u16* p, f16x8 v) {
  asm volatile("global_store_dwordx4 %0, %1, off sc1" :: "v"(p), "v"(v) : "memory");
}
__device__ __forceinline__ f16x8 ld16_sc0(const u16* p) {
  f16x8 v;
  asm volatile("global_load_dwordx4 %0, %1, off sc0" : "=v"(v) : "v"(p) : "memory");
  return v;
}
__device__ __forceinline__ void sttag_sc0(int* p, int v) {
  asm volatile("global_store_dword %0, %1, off sc0" :: "v"(p), "v"(v) : "memory");
}
__device__ __forceinline__ void sttag_sc1(int* p, int v) {
  asm volatile("global_store_dword %0, %1, off sc1" :: "v"(p), "v"(v) : "memory");
}
__device__ __forceinline__ int ldtag_sc0(const int* p) {
  int v;
  asm volatile("global_load_dword %0, %1, off sc0" : "=v"(v) : "v"(p) : "memory");
  return v;
}
__device__ __forceinline__ int ldtag_sc1(const int* p) {
  int v;
  asm volatile("global_load_dword %0, %1, off sc1" : "=v"(v) : "v"(p) : "memory");
  return v;
}

// ---------------- utility kernels ----------------

struct CvtJob { const float* s; u16* d; int n; };
struct CvtJobs { CvtJob j[9]; };

__global__ void cvt_many(CvtJobs jobs) {
  CvtJob jb = jobs.j[blockIdx.y];
  int i = blockIdx.x * 256 + threadIdx.x;
  if (i < jb.n) jb.d[i] = f2h(jb.s[i]);
}

__global__ void bias_init(float* __restrict__ o, const float* __restrict__ b, int n) {
  int i = blockIdx.x * 256 + threadIdx.x;
  if (i < n) o[i] = b[i & 63];
}

__global__ void fill_diag(float* __restrict__ o, int n, float sentinel) {
  int i = blockIdx.x * 256 + threadIdx.x;
  if (i < n) o[i] = (i == 0) ? sentinel : 0.f;
}

// ---------------- GEMM role body (2 waves, 128 threads) ----------------
// gx tiles: 64x128, tiles = 2dirs x 64(tm) x 16(tn) = 2048. Row m = b*32+i.
//   lmode 0: A gathered from emb fp32 via x (layer1, K=256).
//   lmode 1: A gathered from out1 fp16 (layer2, K=1024).
// cls tiles (cls_s0>=0): 128x64, tiles = 2dirs x 32 = 64, K=512 per dir,
//   atomicAdd into bias-initialized dout with packed-seq masking.
// Register-pipelined staging (loads for kt+32 issued during MFMA of kt).

#define GX_LOAD(kt_) do { \
    if (lmode == 0) { \
      rf0 = *(const f32x4*)(Arf + (kt_) + kc); \
      rf1 = *(const f32x4*)(Arf + (kt_) + kc + 4); \
      rf2 = *(const f32x4*)(Arf + (kt_) + kc + 8); \
      rf3 = *(const f32x4*)(Arf + (kt_) + kc + 12); \
    } else { \
      ra0 = *(const uint4*)(Arh + (kt_) + kc); \
      ra1 = *(const uint4*)(Arh + (kt_) + kc + 8); \
    } \
    rb0 = *(const uint4*)(Br0 + (kt_) + kc); \
    rb1 = *(const uint4*)(Br0 + (kt_) + kc + 8); \
    rb2 = *(const uint4*)(Br1 + (kt_) + kc); \
    rb3 = *(const uint4*)(Br1 + (kt_) + kc + 8); \
  } while (0)

#define CLS_LOAD(kt_) do { \
    ca0 = *(const uint4*)(Arow + (kt_)); \
    ca1 = *(const uint4*)(Arow + (kt_) + 8); \
    ca2 = *(const uint4*)(Arow + (kt_) + 16); \
    ca3 = *(const uint4*)(Arow + (kt_) + 24); \
    cb0 = *(const uint4*)(Brw + (kt_) + kc); \
    cb1 = *(const uint4*)(Brw + (kt_) + kc + 8); \
  } while (0)

__device__ __forceinline__ void gemm_body(
    int gb, int nb, int tid,
    int lmode, int do_gx,
    const int* __restrict__ x, const float* __restrict__ emb,
    const u16* __restrict__ out1g,
    const u16* __restrict__ Bf, const u16* __restrict__ Bb,
    const float* __restrict__ biasf, const float* __restrict__ biasb,
    u16* __restrict__ gxn, int s0n, int K,
    int cls_s0, const u16* __restrict__ out2p, const u16* __restrict__ wclsp,
    float* __restrict__ dout, const int* __restrict__ len,
    u16* As, u16* Bs)
{
  const int lane = tid & 63;
  const int m16 = lane & 15, quad = lane >> 4;
  const int wv = tid >> 6;            // wave 0..1
  const int row = tid >> 1;           // 0..63
  const int kc = (tid & 1) * 16;
  const int ngx = do_gx ? 2048 : 0;
  const int ntl = ngx + (cls_s0 >= 0 ? 64 : 0);

  for (int t = gb; t < ntl; t += nb) {
    f32x4 acc[4][4];
#pragma unroll
    for (int a2 = 0; a2 < 4; ++a2)
#pragma unroll
      for (int c2 = 0; c2 < 4; ++c2) acc[a2][c2] = zf4();

    if (t < ngx) {
      // -------- gx tile --------
      const int dir = t >> 10, rem = t & 1023, tm = rem & 63, tn = rem >> 6;
      const u16* Bm = dir ? Bb : Bf;
      const float* bias = dir ? biasb : biasf;
      u16* Cp = gxn + (size_t)dir * 4096 * 2048;
      const int rowm = tm * 64 + row, b = rowm >> 5, ii = rowm & 31, s = s0n + ii;
      int pos;
      if (dir) { int p = len[b] - 1 - s; pos = p < 0 ? 0 : p; } else pos = s;
      const float* Arf = nullptr; const u16* Arh = nullptr;
      if (lmode == 0) Arf = emb + (size_t)x[b * TT + pos] * 256;
      else            Arh = out1g + ((size_t)b * TT + pos) * 1024;
      const u16* Br0 = Bm + (size_t)(tn * 128 + row) * K;
      const u16* Br1 = Bm + (size_t)(tn * 128 + row + 64) * K;

      f32x4 rf0, rf1, rf2, rf3; uint4 ra0, ra1, rb0, rb1, rb2, rb3;
      GX_LOAD(0);
      for (int kt = 0; kt < K; kt += 32) {
        if (lmode == 0) {
          f16x8 v0, v1;
#pragma unroll
          for (int j = 0; j < 4; ++j) {
            v0[j] = (f16)rf0[j]; v0[j + 4] = (f16)rf1[j];
            v1[j] = (f16)rf2[j]; v1[j + 4] = (f16)rf3[j];
          }
          *(f16x8*)&As[row * 40 + kc] = v0;
          *(f16x8*)&As[row * 40 + kc + 8] = v1;
        } else {
          *(uint4*)&As[row * 40 + kc]     = ra0;
          *(uint4*)&As[row * 40 + kc + 8] = ra1;
        }
        *(uint4*)&Bs[row * 40 + kc]            = rb0;
        *(uint4*)&Bs[row * 40 + kc + 8]        = rb1;
        *(uint4*)&Bs[(row + 64) * 40 + kc]     = rb2;
        *(uint4*)&Bs[(row + 64) * 40 + kc + 8] = rb3;
        __syncthreads();
        if (kt + 32 < K) GX_LOAD(kt + 32);
        f16x8 af[4], bfr[4];
#pragma unroll
        for (int mt = 0; mt < 4; ++mt)
          af[mt] = *(const f16x8*)&As[(mt * 16 + m16) * 40 + quad * 8];
#pragma unroll
        for (int nt = 0; nt < 4; ++nt)
          bfr[nt] = *(const f16x8*)&Bs[(wv * 64 + nt * 16 + m16) * 40 + quad * 8];
#pragma unroll
        for (int mt = 0; mt < 4; ++mt)
#pragma unroll
          for (int nt = 0; nt < 4; ++nt)
            acc[mt][nt] = __builtin_amdgcn_mfma_f32_16x16x32_f16(af[mt], bfr[nt], acc[mt][nt], 0, 0, 0);
        __syncthreads();
      }
#pragma unroll
      for (int mt = 0; mt < 4; ++mt)
#pragma unroll
        for (int nt = 0; nt < 4; ++nt) {
          const int n = tn * 128 + wv * 64 + nt * 16 + m16;
          const float bv = bias[n];
#pragma unroll
          for (int r = 0; r < 4; ++r) {
            const int mm = tm * 64 + mt * 16 + quad * 4 + r;
            Cp[(size_t)mm * 2048 + n] = f2h(acc[mt][nt][r] + bv);
          }
        }
    } else {
      // -------- cls tile --------
      const int tc = t - ngx;
      const int dir = tc >> 5, m0 = (tc & 31) * 128;
      const u16* Arow = out2p + (size_t)(m0 + tid) * 1024 + dir * 512;
      const u16* Brw  = wclsp + (size_t)row * 1024 + dir * 512;
      uint4 ca0, ca1, ca2, ca3, cb0, cb1;
      CLS_LOAD(0);
      for (int kt = 0; kt < 512; kt += 32) {
        *(uint4*)&Bs[tid * 40]      = ca0;
        *(uint4*)&Bs[tid * 40 + 8]  = ca1;
        *(uint4*)&Bs[tid * 40 + 16] = ca2;
        *(uint4*)&Bs[tid * 40 + 24] = ca3;
        *(uint4*)&As[row * 40 + kc]     = cb0;
        *(uint4*)&As[row * 40 + kc + 8] = cb1;
        __syncthreads();
        if (kt + 32 < 512) CLS_LOAD(kt + 32);
        f16x8 af[4], bfr[4];
#pragma unroll
        for (int mt = 0; mt < 4; ++mt)
          af[mt] = *(const f16x8*)&Bs[(wv * 64 + mt * 16 + m16) * 40 + quad * 8];
#pragma unroll
        for (int nt = 0; nt < 4; ++nt)
          bfr[nt] = *(const f16x8*)&As[(nt * 16 + m16) * 40 + quad * 8];
#pragma unroll
        for (int mt = 0; mt < 4; ++mt)
#pragma unroll
          for (int nt = 0; nt < 4; ++nt)
            acc[mt][nt] = __builtin_amdgcn_mfma_f32_16x16x32_f16(af[mt], bfr[nt], acc[mt][nt], 0, 0, 0);
        __syncthreads();
      }
#pragma unroll
      for (int mt = 0; mt < 4; ++mt)
#pragma unroll
        for (int nt = 0; nt < 4; ++nt) {
          const int n = nt * 16 + m16;
#pragma unroll
          for (int r = 0; r < 4; ++r) {
            const int m = m0 + wv * 64 + mt * 16 + quad * 4 + r;
            const int b = m >> 5, ii = m & 31, s = cls_s0 + ii;
            const int L = len[b];
            if (s < L) {
              const int pos = dir ? (L - 1 - s) : s;
              atomicAdd(&dout[((size_t)b * TT + pos) * 64 + n], acc[mt][nt][r]);
            }
          }
        }
    }
  }
}

__global__ __launch_bounds__(128, 2) void gemm_all(
    int lmode, int do_gx, const int* __restrict__ x, const float* __restrict__ emb,
    const u16* __restrict__ out1g,
    const u16* __restrict__ Bf, const u16* __restrict__ Bb,
    const float* __restrict__ biasf, const float* __restrict__ biasb,
    u16* __restrict__ gxn, int s0n, int K,
    int cls_s0, const u16* __restrict__ out2p, const u16* __restrict__ wclsp,
    float* __restrict__ dout, const int* __restrict__ len)
{
  __shared__ u16 As[64 * 40];
  __shared__ u16 Bs[128 * 40];
  gemm_body(blockIdx.x, gridDim.x, threadIdx.x, lmode, do_gx, x, emb, out1g,
            Bf, Bb, biasf, biasb, gxn, s0n, K, cls_s0, out2p, wclsp, dout, len,
            As, Bs);
}

// ---------------- fused: persistent BiLSTM scan chunk + overlapped GEMM ----
// Role by XCD RESIDUE (bi&7): <4 -> scan (XCDs 0-3), >=4 -> gemm (XCDs 4-7).
// Scan remap keeps each tag-group on ONE residue:
//   res = bi&7 (0..3), k = bi>>3 (0..63)
//   bg = res*2 + (k&1)   (batch groups 0..7; two per residue)
//   rank = k>>1          (0..31: dir x role)
// GEMM: gb = (bi>>3)*4 + (res-4), stride 256.

__global__ __launch_bounds__(128, 1) void fused(
    const u16* __restrict__ gxc, const u16* __restrict__ whh_f,
    const u16* __restrict__ whh_b, const int* __restrict__ len,
    u16* __restrict__ out_pos, u16* __restrict__ out_chunk,
    u16* __restrict__ hseq, u16* __restrict__ hcarry,
    float* __restrict__ cbuf, int* __restrict__ tags,
    int s0, int tagbase,
    int lmode, int do_gx, const int* __restrict__ x,
    const float* __restrict__ emb, const u16* __restrict__ out1g,
    const u16* __restrict__ Bf, const u16* __restrict__ Bb,
    const float* __restrict__ biasf, const float* __restrict__ biasb,
    u16* __restrict__ gxn, int s0n, int K,
    int cls_s0, const u16* __restrict__ out2p, const u16* __restrict__ wclsp,
    float* __restrict__ dout)
{
  __shared__ u16 As[64 * 40];
  __shared__ u16 Bs[128 * 40];
  __shared__ u16 tb[2][256];                 // 16x16 transpose tile per wave

  const int bix = blockIdx.x;
  const int res = bix & 7;

  if (res >= 4) {
    const int gb = ((bix >> 3) << 2) | (res - 4);   // 0..255
    gemm_body(gb, 256, threadIdx.x, lmode, do_gx, x, emb, out1g,
              Bf, Bb, biasf, biasb, gxn, s0n, K, cls_s0, out2p, wclsp, dout,
              len, As, Bs);
    return;
  }

  const int tid = threadIdx.x;
  const int k = bix >> 3;                    // 0..63 within residue
  const int bg = res * 2 + (k & 1);          // batch-group, same-XCD cohort
  const int rank = k >> 1;                   // 0..31
  const int dir = rank >> 4;
  const int role = rank & 15;
  const int b_base = bg * 16;
  const int grp = dir * 8 + bg;
  const int u_tile = role * 2 + (tid >> 6);  // 0..31 within group
  const int u_base = u_tile * 16;
  const int lane = tid & 63;
  const int m16 = lane & 15, quad = lane >> 4;
  const u16* gxd = gxc + (size_t)dir * 4096 * 2048;
  const u16* whh = dir ? whh_b : whh_f;
  u16* T = tb[tid >> 6];
  int* gtags = tags + grp * 32 * TSTR;
  int* mytag = gtags + u_tile * TSTR;

  // W_hh fragments: B[n=lane&15][k=quad*8+j] — 256 regs, AGPR-resident.
  f16x8 bf[4][16];
#pragma unroll
  for (int g = 0; g < 4; ++g) {
    const u16* wrow = whh + (size_t)(g * HH + u_base + m16) * HH + quad * 8;
#pragma unroll
    for (int ks = 0; ks < 16; ++ks)
      bf[g][ks] = *(const f16x8*)(wrow + ks * 32);
  }

  int lenr[4];
#pragma unroll
  for (int r = 0; r < 4; ++r) lenr[r] = len[b_base + quad * 4 + r];

  float cst[4];
  if (s0 == 0) {
#pragma unroll
    for (int r = 0; r < 4; ++r) cst[r] = 0.f;
  } else {
#pragma unroll
    for (int r = 0; r < 4; ++r)
      cst[r] = cbuf[(size_t)dir * 65536 + (b_base + quad * 4 + r) * HH + u_base + m16];
  }

  const u16* carry_rd = hcarry + (size_t)dir * 65536 + (b_base + m16) * HH + quad * 8;

  // gx prefetch for step 0 (drained by first use in cell math)
  u16 gpre[4][4];
#pragma unroll
  for (int r = 0; r < 4; ++r) {
    const int batch = b_base + quad * 4 + r;
    const u16* gq = gxd + (size_t)(batch * CH + 0) * 2048 + u_base + m16;
    gpre[r][0] = gq[0]; gpre[r][1] = gq[512];
    gpre[r][2] = gq[1024]; gpre[r][3] = gq[1536];
  }

  for (int i = 0; i < CH; ++i) {
    const int s = s0 + i;

    // A fragments = h[s-1]
    f16x8 a[16];
    if (i == 0) {
      if (s0 == 0) {
#pragma unroll
        for (int ks = 0; ks < 16; ++ks)
#pragma unroll
          for (int j = 0; j < 8; ++j) a[ks][j] = (f16)0.f;
      } else {
#pragma unroll
        for (int ks = 0; ks < 16; ++ks)
          a[ks] = *(const f16x8*)(carry_rd + ks * 32);   // kernel-boundary coherent
      }
    } else {
      // tag poll: alternate sc0 (fast when co-located) and sc1 (always-fresh LLC).
      const int want = tagbase + i;
      const int* myp = gtags + (lane & 31) * TSTR;
      int it = 0;
      while (true) {
        int t = (it & 1) ? ldtag_sc1(myp) : ldtag_sc0(myp);
        asm volatile("s_waitcnt vmcnt(0)" ::: "memory");
        if (__ballot(t < want) == 0ull) break;
        ++it;
        __builtin_amdgcn_s_sleep(1);
      }
      // h loads sc0: first-touch slots this dispatch — dirty-L2 hit
      // (co-located producer) or LLC fill (sc1 order guarantees currency).
      const u16* sb = hseq + ((size_t)(dir * CH + (i - 1)) * 128 + b_base + m16) * HH + quad * 8;
#pragma unroll
      for (int ks = 0; ks < 16; ++ks) a[ks] = ld16_sc0(sb + ks * 32);
      asm volatile("s_waitcnt vmcnt(0)" ::: "memory");
    }

    f32x4 a0 = zf4(), a1 = zf4(), a2 = zf4(), a3 = zf4();
#pragma unroll
    for (int ks = 0; ks < 16; ++ks) {
      a0 = __builtin_amdgcn_mfma_f32_16x16x32_f16(a[ks], bf[0][ks], a0, 0, 0, 0);
      a1 = __builtin_amdgcn_mfma_f32_16x16x32_f16(a[ks], bf[1][ks], a1, 0, 0, 0);
      a2 = __builtin_amdgcn_mfma_f32_16x16x32_f16(a[ks], bf[2][ks], a2, 0, 0, 0);
      a3 = __builtin_amdgcn_mfma_f32_16x16x32_f16(a[ks], bf[3][ks], a3, 0, 0, 0);
    }

    // cell math
    u16 hv[4];
#pragma unroll
    for (int r = 0; r < 4; ++r) {
      float gi = a0[r] + h2f(gpre[r][0]);
      float gf = a1[r] + h2f(gpre[r][1]);
      float gg = a2[r] + h2f(gpre[r][2]);
      float go = a3[r] + h2f(gpre[r][3]);
      float c = sigf(gf) * cst[r] + sigf(gi) * tanhf_(gg);
      cst[r] = c;
      hv[r] = f2h(sigf(go) * tanhf_(c));
    }

    // publish h: LDS 16x16 transpose -> split-scope stores + tags
#pragma unroll
    for (int r = 0; r < 4; ++r)
      T[(quad * 4 + r) * 16 + m16] = hv[r];
    if (i == CH - 1) {
      if (lane < 32) {
        const int brow = lane >> 1, col8 = (lane & 1) * 8;
        f16x8 hrow = *(const f16x8*)&T[brow * 16 + col8];
        *(f16x8*)(hcarry + (size_t)dir * 65536 + (b_base + brow) * HH + u_base + col8) = hrow;
      }
    } else {
      u16* dst = nullptr; f16x8 hrow;
      if (lane < 32) {
        const int brow = lane >> 1, col8 = (lane & 1) * 8;
        hrow = *(const f16x8*)&T[brow * 16 + col8];
        dst = hseq + ((size_t)(dir * CH + i) * 128 + b_base + brow) * HH + u_base + col8;
        st16_sc0(dst, hrow);
      }
      asm volatile("s_waitcnt vmcnt(0)" ::: "memory");   // h at own-XCD L2
      if (lane == 0) sttag_sc0(mytag, tagbase + i + 1);
      if (lane < 32) st16_sc1(dst, hrow);
      asm volatile("s_waitcnt vmcnt(0)" ::: "memory");   // h at LLC
      if (lane == 0) sttag_sc1(mytag, tagbase + i + 1);
    }

    // gx prefetch for step i+1 (issued early; drained by next poll/use)
    if (i + 1 < CH) {
#pragma unroll
      for (int r = 0; r < 4; ++r) {
        const int batch = b_base + quad * 4 + r;
        const u16* gq = gxd + (size_t)(batch * CH + (i + 1)) * 2048 + u_base + m16;
        gpre[r][0] = gq[0]; gpre[r][1] = gq[512];
        gpre[r][2] = gq[1024]; gpre[r][3] = gq[1536];
      }
    }

    // outputs (plain stores, off the publish path)
#pragma unroll
    for (int r = 0; r < 4; ++r) {
      const int batch = b_base + quad * 4 + r;
      const int L = lenr[r];
      const bool valid = s < L;
      if (out_pos) {
        const int p = dir ? (L - 1 - s) : s;
        const int wrow = valid ? (p < 0 ? 0 : p) : s;
        out_pos[(size_t)(batch * TT + wrow) * 1024 + dir * 512 + u_base + m16]
            = valid ? hv[r] : (u16)0;
      } else {
        out_chunk[(size_t)(batch * CH + i) * 1024 + dir * 512 + u_base + m16] = hv[r];
      }
    }
  }

#pragma unroll
  for (int r = 0; r < 4; ++r)
    cbuf[(size_t)dir * 65536 + (b_base + quad * 4 + r) * HH + u_base + m16] = cst[r];
}

// ---------------- launch ----------------

extern "C" void kernel_launch(void* const* d_in, const int* in_sizes, int n_in,
                              void* d_out, int out_size, void* d_ws, size_t ws_size,
                              hipStream_t stream) {
  const int*   x      = (const int*)d_in[0];
  const int*   len    = (const int*)d_in[1];
  const float* emb    = (const float*)d_in[2];
  const float* Wih_f1 = (const float*)d_in[3];
  const float* Whh_f1 = (const float*)d_in[4];
  const float* b_f1   = (const float*)d_in[5];
  const float* Wih_b1 = (const float*)d_in[6];
  const float* Whh_b1 = (const float*)d_in[7];
  const float* b_b1   = (const float*)d_in[8];
  const float* Wih_f2 = (const float*)d_in[9];
  const float* Whh_f2 = (const float*)d_in[10];
  const float* b_f2   = (const float*)d_in[11];
  const float* Wih_b2 = (const float*)d_in[12];
  const float* Whh_b2 = (const float*)d_in[13];
  const float* b_b2   = (const float*)d_in[14];
  const float* W_cls  = (const float*)d_in[15];
  const float* b_cls  = (const float*)d_in[16];

  const size_t GXC1  = (size_t)2 * 4096 * 2048 * 2;     // 33.5 MB per parity
  const size_t OUT1  = (size_t)65536 * 1024 * 2;        // 128 MB
  const size_t OUT2  = (size_t)4096 * 1024 * 2;         // 8 MB per parity
  const size_t WTS   = (size_t)9502720 * 2;             // 18.1 MB
  const size_t HSEQ  = (size_t)2 * CH * 128 * 512 * 2;  // 8 MB
  const size_t HCAR  = (size_t)2 * 128 * 512 * 2;       // 256 KB
  const size_t TAGSZ = 16 * 32 * TSTR * 4;              // 32 KB
  const size_t NEED = 2 * GXC1 + OUT1 + 2 * OUT2 + WTS + HSEQ + HCAR + 524288 + TAGSZ;
  if (ws_size < NEED) {
    fill_diag<<<dim3((out_size + 255) / 256), dim3(256), 0, stream>>>(
        (float*)d_out, out_size, (float)(ws_size >> 20));
    return;
  }

  char* w = (char*)d_ws;
  u16* gxb0  = (u16*)w; w += GXC1;
  u16* gxb1  = (u16*)w; w += GXC1;
  u16* out1  = (u16*)w; w += OUT1;
  u16* o2b0  = (u16*)w; w += OUT2;
  u16* o2b1  = (u16*)w; w += OUT2;
  u16* wihf1 = (u16*)w; w += (size_t)2048 * 256 * 2;
  u16* wihb1 = (u16*)w; w += (size_t)2048 * 256 * 2;
  u16* whhf1 = (u16*)w; w += (size_t)2048 * 512 * 2;
  u16* whhb1 = (u16*)w; w += (size_t)2048 * 512 * 2;
  u16* wihf2 = (u16*)w; w += (size_t)2048 * 1024 * 2;
  u16* wihb2 = (u16*)w; w += (size_t)2048 * 1024 * 2;
  u16* whhf2 = (u16*)w; w += (size_t)2048 * 512 * 2;
  u16* whhb2 = (u16*)w; w += (size_t)2048 * 512 * 2;
  u16* wcls  = (u16*)w; w += (size_t)64 * 1024 * 2;
  u16* hseq  = (u16*)w; w += HSEQ;
  u16* hcarry = (u16*)w; w += HCAR;
  float* cbuf = (float*)w; w += 524288;
  int* tags  = (int*)w; w += TAGSZ;

  CvtJobs jobs = {{
    { Wih_f1, wihf1, 2048 * 256 }, { Wih_b1, wihb1, 2048 * 256 },
    { Whh_f1, whhf1, 2048 * 512 }, { Whh_b1, whhb1, 2048 * 512 },
    { Wih_f2, wihf2, 2048 * 1024 }, { Wih_b2, wihb2, 2048 * 1024 },
    { Whh_f2, whhf2, 2048 * 512 }, { Whh_b2, whhb2, 2048 * 512 },
    { W_cls,  wcls,  64 * 1024 },
  }};
  cvt_many<<<dim3(8192, 9), dim3(256), 0, stream>>>(jobs);
  bias_init<<<dim3(16384), dim3(256), 0, stream>>>((float*)d_out, b_cls, 65536 * 64);
  hipMemsetAsync(tags, 0, TAGSZ, stream);   // tags monotone within one launch set

  u16* gxb[2] = { gxb0, gxb1 };
  u16* o2b[2] = { o2b0, o2b1 };
  float* doutf = (float*)d_out;

  int seq = 0;
  // ---- layer 1 ----
  gemm_all<<<dim3(2048), dim3(128), 0, stream>>>(
      0, 1, x, emb, nullptr, wihf1, wihb1, b_f1, b_b1,
      gxb[0], 0, 256, -1, nullptr, wcls, doutf, len);
  for (int c = 0; c < NCH; ++c) {
    fused<<<dim3(512), dim3(128), 0, stream>>>(
        gxb[c & 1], whhf1, whhb1, len, out1, nullptr, hseq, hcarry, cbuf, tags,
        c * CH, seq * CH,
        0, (c < NCH - 1) ? 1 : 0, x, emb, nullptr, wihf1, wihb1, b_f1, b_b1,
        gxb[(c + 1) & 1], (c + 1) * CH, 256,
        -1, nullptr, wcls, doutf);
    ++seq;
  }
  // ---- layer 2 + overlapped classifier ----
  gemm_all<<<dim3(2048), dim3(128), 0, stream>>>(
      1, 1, x, emb, out1, wihf2, wihb2, b_f2, b_b2,
      gxb[0], 0, 1024, -1, nullptr, wcls, doutf, len);
  for (int c = 0; c < NCH; ++c) {
    fused<<<dim3(512), dim3(128), 0, stream>>>(
        gxb[c & 1], whhf2, whhb2, len, nullptr, o2b[c & 1], hseq, hcarry, cbuf, tags,
        c * CH, seq * CH,
        1, (c < NCH - 1) ? 1 : 0, x, emb, out1, wihf2, wihb2, b_f2, b_b2,
        gxb[(c + 1) & 1], (c + 1) * CH, 1024,
        (c >= 1) ? (c - 1) * CH : -1, o2b[(c & 1) ^ 1], wcls, doutf);
    ++seq;
  }
  // tail classifier for the last chunk
  gemm_all<<<dim3(64), dim3(128), 0, stream>>>(
      1, 0, x, emb, out1, wihf2, wihb2, b_f2, b_b2,
      gxb[0], 0, 1024, (NCH - 1) * CH, o2b[(NCH - 1) & 1], wcls, doutf, len);
}